// Round 8
// baseline (275.549 us; speedup 1.0000x reference)
//
#include <hip/hip_runtime.h>
#include <hip/hip_bf16.h>
#include <stdint.h>

// B=8, L=4096, T=512, D_H=1280, D_G=768, D_P=256, scale = 1/16

typedef float f32x4 __attribute__((ext_vector_type(4)));
typedef short bf16x8 __attribute__((ext_vector_type(8)));

__device__ __forceinline__ unsigned short f2bf(float f) {
    __hip_bfloat16 h = __float2bfloat16(f);
    return __builtin_bit_cast(unsigned short, h);
}
__device__ __forceinline__ float bf2f(unsigned short h) {
    union { uint32_t u; float f; } v; v.u = ((uint32_t)h) << 16;
    return v.f;
}

// bijective XCD-chunk swizzle (gridDim.x % 8 == 0 at all call sites)
__device__ __forceinline__ int xcdswz(int bx, int nbx) {
    int cpx = nbx >> 3;
    return (bx & 7) * cpx + (bx >> 3);
}

// async global->LDS, 16B per lane; LDS dest = wave-uniform base + lane*16
__device__ __forceinline__ void gload16(const unsigned short* g, unsigned short* l) {
    __builtin_amdgcn_global_load_lds(
        (const __attribute__((address_space(1))) void*)g,
        (__attribute__((address_space(3))) void*)l,
        16, 0, 0);
}

// LDS index for f32-staged kernels (padded stride 40 + granule XOR swizzle)
__device__ __forceinline__ int lidx(int row, int kshort) {
    return row * 40 + (((kshort >> 3) ^ ((row >> 3) & 3)) << 3) + (kshort & 7);
}

// ---------------------------------------------------------------------------
// f32 -> bf16 contiguous convert (for Wk); n4 = count/4
// ---------------------------------------------------------------------------
__global__ __launch_bounds__(256)
void cvt_f32_bf16(const float* __restrict__ in, unsigned short* __restrict__ out, long n4)
{
    long i = (long)blockIdx.x * 256 + threadIdx.x;
    if (i >= n4) return;
    float4 v = ((const float4*)in)[i];
    ushort4 w;
    w.x = f2bf(v.x); w.y = f2bf(v.y); w.z = f2bf(v.z); w.w = f2bf(v.w);
    ((ushort4*)out)[i] = w;
}

// ---------------------------------------------------------------------------
// H [8][4096][1280] f32 -> Hbt [8][1280][4096] bf16 (transposed)
//                       -> Hb  [8][4096][1280] bf16 (row-major, coalesced)
// ---------------------------------------------------------------------------
template<bool WRITE_HB>
__global__ __launch_bounds__(256)
void cvt_h(const float* __restrict__ H, unsigned short* __restrict__ Hbt,
           unsigned short* __restrict__ Hb)
{
    __shared__ unsigned short lT[64 * 72];
    const int ntile = 64 * 20 * 8;
    for (int tileid = blockIdx.x; tileid < ntile; tileid += gridDim.x) {
        int tmp = tileid;
        const int dt = tmp % 20; tmp /= 20;
        const int lt = tmp % 64;
        const int b  = tmp / 64;
        const int l0 = lt * 64, d0 = dt * 64;
        const float* Hs = H + ((long)b * 4096 + l0) * 1280 + d0;
        #pragma unroll
        for (int it = 0; it < 4; ++it) {
            int chunk = it * 256 + threadIdx.x;
            int lr = chunk >> 4, dc4 = (chunk & 15) << 2;
            float4 v = *(const float4*)(Hs + (long)lr * 1280 + dc4);
            unsigned short w[4] = { f2bf(v.x), f2bf(v.y), f2bf(v.z), f2bf(v.w) };
            if constexpr (WRITE_HB) {
                ushort4 wb = { w[0], w[1], w[2], w[3] };
                *(ushort4*)(Hb + ((long)b * 4096 + l0 + lr) * 1280 + d0 + dc4) = wb;
            }
            #pragma unroll
            for (int j = 0; j < 4; ++j) {
                int d = dc4 + j;
                int sl = (lr & 15) | ((((lr >> 4) ^ (d >> 2)) & 3) << 4);
                lT[d * 72 + sl] = w[j];
            }
        }
        __syncthreads();
        {
            int drow = threadIdx.x >> 2, lc = threadIdx.x & 3;
            int slc = lc ^ ((drow >> 2) & 3);
            const uint4* src = (const uint4*)(lT + drow * 72 + slc * 16);
            unsigned short* dst = Hbt + ((long)b * 1280 + d0 + drow) * 4096 + l0 + lc * 16;
            uint4 v0 = src[0], v1 = src[1];
            *(uint4*)(dst)     = v0;
            *(uint4*)(dst + 8) = v1;
        }
        __syncthreads();
    }
}

// ---------------------------------------------------------------------------
// Projection GEMM: f32 inputs (cvt in staging), bf16 out. 128x128, BK=32.
// ---------------------------------------------------------------------------
__global__ __launch_bounds__(256)
void gemm_proj(const float* __restrict__ Ap, const float* __restrict__ Bp,
               unsigned short* __restrict__ Cp, int M, int N, int K)
{
    __shared__ __align__(16) unsigned short lA[128 * 40];
    __shared__ __align__(16) unsigned short lB[128 * 40];

    const int bx = xcdswz(blockIdx.x, gridDim.x);
    const int nt = N >> 7;
    const int tm = bx / nt;
    const int tn = bx % nt;
    const int tid = threadIdx.x;
    const int lane = tid & 63, wv = tid >> 6;
    const int wr = wv >> 1, wc = wv & 1;
    const int fr = lane & 15, fk = lane >> 4;

    f32x4 acc[4][4] = {};

    for (int k0 = 0; k0 < K; k0 += 32) {
        {
            const float* A = Ap + (long)tm * 128 * K + k0;
            #pragma unroll
            for (int it = 0; it < 4; ++it) {
                int chunk = it * 256 + tid;
                int row = chunk >> 3;
                int kc  = (chunk & 7) << 2;
                const float4 v = *(const float4*)(A + (long)row * K + kc);
                ushort4 w;
                w.x = f2bf(v.x); w.y = f2bf(v.y); w.z = f2bf(v.z); w.w = f2bf(v.w);
                *(ushort4*)(&lA[lidx(row, kc)]) = w;
            }
        }
        {
            const float* B = Bp + (long)tn * 128 * K + k0;
            #pragma unroll
            for (int it = 0; it < 4; ++it) {
                int chunk = it * 256 + tid;
                int row = chunk >> 3;
                int kc  = (chunk & 7) << 2;
                const float4 v = *(const float4*)(B + (long)row * K + kc);
                ushort4 w;
                w.x = f2bf(v.x); w.y = f2bf(v.y); w.z = f2bf(v.z); w.w = f2bf(v.w);
                *(ushort4*)(&lB[lidx(row, kc)]) = w;
            }
        }
        __syncthreads();
        bf16x8 af[4], bfr[4];
        #pragma unroll
        for (int i = 0; i < 4; ++i)
            af[i] = *(const bf16x8*)(&lA[lidx(wr * 64 + i * 16 + fr, fk * 8)]);
        #pragma unroll
        for (int i = 0; i < 4; ++i)
            bfr[i] = *(const bf16x8*)(&lB[lidx(wc * 64 + i * 16 + fr, fk * 8)]);
        #pragma unroll
        for (int mi = 0; mi < 4; ++mi)
            #pragma unroll
            for (int ni = 0; ni < 4; ++ni)
                acc[mi][ni] = __builtin_amdgcn_mfma_f32_16x16x32_bf16(af[mi], bfr[ni], acc[mi][ni], 0, 0, 0);
        __syncthreads();
    }

    unsigned short* C = Cp + ((long)tm * 128) * N + (long)tn * 128;
    #pragma unroll
    for (int mi = 0; mi < 4; ++mi)
        #pragma unroll
        for (int ni = 0; ni < 4; ++ni)
            #pragma unroll
            for (int j = 0; j < 4; ++j) {
                int m = wr * 64 + mi * 16 + fk * 4 + j;
                int n = wc * 64 + ni * 16 + fr;
                C[(long)m * N + n] = f2bf(acc[mi][ni][j]);
            }
}

// ---------------------------------------------------------------------------
// All-bf16 C = scale*A@B^T (m97 structure). Tile 128x128, BK=64, 4 waves 2x2.
// gload16 staging, pre-swizzled source + XOR-swizzled reads. OF32: f32 out.
// ---------------------------------------------------------------------------
template<bool OF32>
__global__ __launch_bounds__(256)
void gemm_bt16s(const unsigned short* __restrict__ Ap, const unsigned short* __restrict__ Bp,
                void* __restrict__ Cp, int M, int N, int K,
                long sA, long sB, long sC, float scale)
{
    __shared__ __align__(16) unsigned short lA[128 * 64];   // 16KB
    __shared__ __align__(16) unsigned short lB[128 * 64];   // 16KB

    const int bx = xcdswz(blockIdx.x, gridDim.x);
    const int nt = N >> 7;
    const int tm = bx / nt, tn = bx % nt;
    const int b  = blockIdx.y;
    const int tid = threadIdx.x;
    const int lane = tid & 63, wv = tid >> 6;
    const int wr = wv >> 1, wc = wv & 1;
    const int fr = lane & 15, fk = lane >> 4;

    f32x4 acc[4][4] = {};

    const unsigned short* A0 = Ap + (long)b * sA + (long)tm * 128 * K;
    const unsigned short* B0 = Bp + (long)b * sB + (long)tn * 128 * K;

    for (int k0 = 0; k0 < K; k0 += 64) {
        #pragma unroll
        for (int q = 0; q < 4; ++q) {
            int slot = wv * 256 + q * 64 + lane;
            int row = slot >> 3, c = slot & 7;
            int ks = (c ^ (row & 7)) << 3;                 // pre-swizzled source chunk
            gload16(A0 + (long)row * K + k0 + ks, lA + (size_t)(wv * 256 + q * 64) * 8);
            gload16(B0 + (long)row * K + k0 + ks, lB + (size_t)(wv * 256 + q * 64) * 8);
        }
        __syncthreads();
        bf16x8 af[2][4], bfv[2][4];
        #pragma unroll
        for (int ks = 0; ks < 2; ++ks) {
            int csw = ((ks * 4 + fk) ^ (fr & 7)) << 3;
            #pragma unroll
            for (int i = 0; i < 4; ++i) {
                af[ks][i]  = *(const bf16x8*)(lA + (wr * 64 + i * 16 + fr) * 64 + csw);
                bfv[ks][i] = *(const bf16x8*)(lB + (wc * 64 + i * 16 + fr) * 64 + csw);
            }
        }
        #pragma unroll
        for (int mi = 0; mi < 4; ++mi)
            #pragma unroll
            for (int ni = 0; ni < 4; ++ni)
                #pragma unroll
                for (int ks = 0; ks < 2; ++ks)
                    acc[mi][ni] = __builtin_amdgcn_mfma_f32_16x16x32_bf16(af[ks][mi], bfv[ks][ni], acc[mi][ni], 0, 0, 0);
        __syncthreads();
    }

    if constexpr (OF32) {
        float* C = (float*)Cp + (long)b * sC + ((long)tm * 128) * N + (long)tn * 128;
        #pragma unroll
        for (int mi = 0; mi < 4; ++mi)
            #pragma unroll
            for (int ni = 0; ni < 4; ++ni)
                #pragma unroll
                for (int j = 0; j < 4; ++j) {
                    int m = wr * 64 + mi * 16 + fk * 4 + j;
                    int n = wc * 64 + ni * 16 + fr;
                    C[(long)m * N + n] = acc[mi][ni][j] * scale;
                }
    } else {
        unsigned short* C = (unsigned short*)Cp + (long)b * sC + ((long)tm * 128) * N + (long)tn * 128;
        #pragma unroll
        for (int mi = 0; mi < 4; ++mi)
            #pragma unroll
            for (int ni = 0; ni < 4; ++ni)
                #pragma unroll
                for (int j = 0; j < 4; ++j) {
                    int m = wr * 64 + mi * 16 + fk * 4 + j;
                    int n = wc * 64 + ni * 16 + fr;
                    C[(long)m * N + n] = f2bf(acc[mi][ni][j] * scale);
                }
    }
}

// ---------------------------------------------------------------------------
// Z partial GEMM with K-split x4: each block computes a full 128x128 f32 tile
// over a 1024-wide K slice. Same staging/compute structure as gemm_bt16s.
// Grid (160, 8): bx -> ks(0..3) * 40 + tn(0..9) * 4 + tm(0..3)  [tm fastest:
// the 4 B-panel sharers are XCD-chunk-adjacent -> Hbt fetched ~once].
// ---------------------------------------------------------------------------
__global__ __launch_bounds__(256)
void zsplit(const unsigned short* __restrict__ Sb, const unsigned short* __restrict__ Hbt,
            float* __restrict__ Zp)
{
    __shared__ __align__(16) unsigned short lA[128 * 64];
    __shared__ __align__(16) unsigned short lB[128 * 64];

    const int K = 4096, N = 1280, KS = 1024;
    const long nZ = (long)8 * 512 * 1280;

    const int bx = xcdswz(blockIdx.x, gridDim.x);    // 160 blocks
    const int tm = bx & 3;
    const int tn = (bx >> 2) % 10;
    const int ks = bx / 40;
    const int b  = blockIdx.y;
    const int tid = threadIdx.x;
    const int lane = tid & 63, wv = tid >> 6;
    const int wr = wv >> 1, wc = wv & 1;
    const int fr = lane & 15, fk = lane >> 4;

    f32x4 acc[4][4] = {};

    const unsigned short* A0 = Sb  + ((long)b * 512  + tm * 128) * K + ks * KS;
    const unsigned short* B0 = Hbt + ((long)b * 1280 + tn * 128) * K + ks * KS;

    for (int k0 = 0; k0 < KS; k0 += 64) {
        #pragma unroll
        for (int q = 0; q < 4; ++q) {
            int slot = wv * 256 + q * 64 + lane;
            int row = slot >> 3, c = slot & 7;
            int kc = (c ^ (row & 7)) << 3;
            gload16(A0 + (long)row * K + k0 + kc, lA + (size_t)(wv * 256 + q * 64) * 8);
            gload16(B0 + (long)row * K + k0 + kc, lB + (size_t)(wv * 256 + q * 64) * 8);
        }
        __syncthreads();
        bf16x8 af[2][4], bfv[2][4];
        #pragma unroll
        for (int kk = 0; kk < 2; ++kk) {
            int csw = ((kk * 4 + fk) ^ (fr & 7)) << 3;
            #pragma unroll
            for (int i = 0; i < 4; ++i) {
                af[kk][i]  = *(const bf16x8*)(lA + (wr * 64 + i * 16 + fr) * 64 + csw);
                bfv[kk][i] = *(const bf16x8*)(lB + (wc * 64 + i * 16 + fr) * 64 + csw);
            }
        }
        #pragma unroll
        for (int mi = 0; mi < 4; ++mi)
            #pragma unroll
            for (int ni = 0; ni < 4; ++ni)
                #pragma unroll
                for (int kk = 0; kk < 2; ++kk)
                    acc[mi][ni] = __builtin_amdgcn_mfma_f32_16x16x32_bf16(af[kk][mi], bfv[kk][ni], acc[mi][ni], 0, 0, 0);
        __syncthreads();
    }

    float* C = Zp + (long)ks * nZ + ((long)b * 512 + tm * 128) * N + tn * 128;
    #pragma unroll
    for (int mi = 0; mi < 4; ++mi)
        #pragma unroll
        for (int ni = 0; ni < 4; ++ni)
            #pragma unroll
            for (int j = 0; j < 4; ++j) {
                int m = wr * 64 + mi * 16 + fk * 4 + j;
                int n = wc * 64 + ni * 16 + fr;
                C[(long)m * N + n] = acc[mi][ni][j];
            }
}

// ---------------------------------------------------------------------------
// out = p0 + p1 + p2 + p3 (deterministic pairwise order), f32x4 elementwise
// ---------------------------------------------------------------------------
__global__ __launch_bounds__(256)
void reduce4(const float* __restrict__ p, float* __restrict__ out, long n4)
{
    long i = (long)blockIdx.x * 256 + threadIdx.x;
    if (i >= n4) return;
    const long s = n4;   // partial stride in f32x4 units
    f32x4 a = ((const f32x4*)p)[i];
    f32x4 b = ((const f32x4*)p)[i + s];
    f32x4 c = ((const f32x4*)p)[i + 2 * s];
    f32x4 d = ((const f32x4*)p)[i + 3 * s];
    ((f32x4*)out)[i] = (a + b) + (c + d);
}

// ---------------------------------------------------------------------------
// Fallback Z-GEMM (small-ws path): C = A(bf16) @ B(f32,[K][N])
// ---------------------------------------------------------------------------
__global__ __launch_bounds__(256)
void gemm_kn(const unsigned short* __restrict__ Ap, const float* __restrict__ Bp,
             float* __restrict__ Cp, int M, int N, int K,
             long sA, long sB, long sC)
{
    __shared__ __align__(16) unsigned short lA[128 * 40];
    __shared__ __align__(16) unsigned short lB[64 * 40];

    const int bx = xcdswz(blockIdx.x, gridDim.x);
    const int mt = M >> 7;
    const int tm = bx % mt;
    const int tn = bx / mt;
    const int b  = blockIdx.y;
    const int tid = threadIdx.x;
    const int lane = tid & 63, wv = tid >> 6;
    const int wr = wv >> 1, wc = wv & 1;
    const int fr = lane & 15, fk = lane >> 4;

    f32x4 acc[4][2] = {};

    const unsigned short* A0 = Ap + (long)b * sA + (long)tm * 128 * K;
    const int nn    = tid & 63;
    const int khalf = tid >> 6;

    for (int k0 = 0; k0 < K; k0 += 32) {
        #pragma unroll
        for (int it = 0; it < 2; ++it) {
            int chunk = it * 256 + tid;
            int row = chunk >> 2;
            int kc  = (chunk & 3) << 3;
            *(uint4*)(&lA[lidx(row, kc)]) = *(const uint4*)(A0 + (long)row * K + k0 + kc);
        }
        {
            const float* Bb = Bp + (long)b * sB + (long)(k0 + khalf * 8) * N + (long)tn * 64 + nn;
            unsigned short t8[8];
            #pragma unroll
            for (int kk = 0; kk < 8; ++kk)
                t8[kk] = f2bf(Bb[(long)kk * N]);
            *(uint4*)(&lB[lidx(nn, khalf * 8)]) = *(uint4*)(&t8[0]);
        }
        __syncthreads();
        bf16x8 af[4], bfr[2];
        #pragma unroll
        for (int i = 0; i < 4; ++i)
            af[i] = *(const bf16x8*)(&lA[lidx(wr * 64 + i * 16 + fr, fk * 8)]);
        #pragma unroll
        for (int i = 0; i < 2; ++i)
            bfr[i] = *(const bf16x8*)(&lB[lidx(wc * 32 + i * 16 + fr, fk * 8)]);
        #pragma unroll
        for (int mi = 0; mi < 4; ++mi)
            #pragma unroll
            for (int ni = 0; ni < 2; ++ni)
                acc[mi][ni] = __builtin_amdgcn_mfma_f32_16x16x32_bf16(af[mi], bfr[ni], acc[mi][ni], 0, 0, 0);
        __syncthreads();
    }

    float* C = Cp + (long)b * sC + ((long)tm * 128) * N + (long)tn * 64;
    #pragma unroll
    for (int mi = 0; mi < 4; ++mi)
        #pragma unroll
        for (int ni = 0; ni < 2; ++ni)
            #pragma unroll
            for (int j = 0; j < 4; ++j) {
                int m = wr * 64 + mi * 16 + fk * 4 + j;
                int n = wc * 32 + ni * 16 + fr;
                C[(long)m * N + n] = acc[mi][ni][j];
            }
}

// ---------------------------------------------------------------------------
// Row softmax in place on S (bf16), rows of length 4096.
// ---------------------------------------------------------------------------
__global__ __launch_bounds__(256)
void softmax_rows(unsigned short* __restrict__ S, const unsigned char* __restrict__ mask)
{
    const int row = blockIdx.x;
    const int b = row >> 9;
    const long base = (long)row * 4096;
    const int tid = threadIdx.x, lane = tid & 63, wv = tid >> 6;
    __shared__ float red[8];

    uint4 s0 = *(const uint4*)(S + base + tid * 16);
    uint4 s1 = *(const uint4*)(S + base + tid * 16 + 8);
    uint4 mv = *(const uint4*)(mask + (long)b * 4096 + tid * 16);
    const unsigned char* mb = (const unsigned char*)&mv;

    unsigned int words[8] = { s0.x, s0.y, s0.z, s0.w, s1.x, s1.y, s1.z, s1.w };
    float x[16];
    #pragma unroll
    for (int i = 0; i < 8; ++i) {
        x[2 * i]     = bf2f((unsigned short)(words[i] & 0xffffu));
        x[2 * i + 1] = bf2f((unsigned short)(words[i] >> 16));
    }
    #pragma unroll
    for (int i = 0; i < 16; ++i)
        if (mb[i]) x[i] = -1e30f;

    float m = x[0];
    #pragma unroll
    for (int i = 1; i < 16; ++i) m = fmaxf(m, x[i]);
    #pragma unroll
    for (int off = 32; off; off >>= 1) m = fmaxf(m, __shfl_xor(m, off));
    if (lane == 0) red[wv] = m;
    __syncthreads();
    m = fmaxf(fmaxf(red[0], red[1]), fmaxf(red[2], red[3]));

    float p[16];
    float s = 0.f;
    #pragma unroll
    for (int i = 0; i < 16; ++i) { p[i] = __expf(x[i] - m); s += p[i]; }
    #pragma unroll
    for (int off = 32; off; off >>= 1) s += __shfl_xor(s, off);
    if (lane == 0) red[4 + wv] = s;
    __syncthreads();
    s = (red[4] + red[5]) + (red[6] + red[7]);
    const float inv = 1.0f / s;

    unsigned int ow[8];
    #pragma unroll
    for (int i = 0; i < 8; ++i) {
        unsigned int lo = f2bf(p[2 * i] * inv);
        unsigned int hi = f2bf(p[2 * i + 1] * inv);
        ow[i] = lo | (hi << 16);
    }
    uint4 o0 = { ow[0], ow[1], ow[2], ow[3] };
    uint4 o1 = { ow[4], ow[5], ow[6], ow[7] };
    *(uint4*)(S + base + tid * 16)     = o0;
    *(uint4*)(S + base + tid * 16 + 8) = o1;
}

// ---------------------------------------------------------------------------
extern "C" void kernel_launch(void* const* d_in, const int* in_sizes, int n_in,
                              void* d_out, int out_size, void* d_ws, size_t ws_size,
                              hipStream_t stream)
{
    const float*         H    = (const float*)d_in[0];
    const float*         G    = (const float*)d_in[1];
    const unsigned char* mask = (const unsigned char*)d_in[2];
    const float*         Wk   = (const float*)d_in[3];
    const float*         Wq   = (const float*)d_in[4];
    float*               out  = (float*)d_out;

    const long nK = (long)8 * 4096 * 256;     // Kb
    const long nQ = (long)8 * 512 * 256;      // Qb
    const long nS = (long)8 * 512 * 4096;     // Sb
    const long nH = (long)8 * 1280 * 4096;    // Hbt / Hb each
    const long nW = (long)256 * 1280;         // Wkb
    const long nZ = (long)8 * 512 * 1280;     // Z elems (f32)

    unsigned short* Kb  = (unsigned short*)d_ws;
    unsigned short* Qb  = Kb + nK;
    unsigned short* Sb  = Qb + nQ;
    unsigned short* Hbt = Sb + nS;
    unsigned short* Hb  = Hbt + nH;
    unsigned short* Wkb = Hb + nH;
    float*          Zp  = (float*)Hb;         // reuse: Hb dead after K-proj;
                                              // 4 * nZ * 4B == nH * 2B exactly

    const size_t need2 = (size_t)(nK + nQ + nS + nH + nH + nW) * 2;  // ~221 MB
    const size_t need1 = (size_t)(nK + nQ + nS + nH) * 2;            // ~137 MB

    if (ws_size >= need2) {
        // 1) Wkb = bf16(Wk)
        cvt_f32_bf16<<<dim3(320), 256, 0, stream>>>(Wk, Wkb, nW / 4);
        // 2) Hb (row-major bf16) + Hbt (transposed bf16) from H, single pass
        cvt_h<true><<<dim3(2048), 256, 0, stream>>>(H, Hbt, Hb);
        // 3) K = Hb @ Wkb^T  (M=32768,N=256,K=1280)
        gemm_bt16s<false><<<dim3(512, 1), 256, 0, stream>>>(
            Hb, Wkb, Kb, 32768, 256, 1280, 0, 0, 0, 1.0f);
        // 4) Q = G @ Wq^T (M=4096,N=256,K=768), f32-staged (small)
        gemm_proj<<<dim3(64, 1), 256, 0, stream>>>(G, Wq, Qb, 4096, 256, 768);
        // 5) S = Q @ K^T * scale  per batch (M=512,N=4096,K=256)
        gemm_bt16s<false><<<dim3(128, 8), 256, 0, stream>>>(
            Qb, Kb, Sb, 512, 4096, 256,
            (long)512 * 256, (long)4096 * 256, (long)512 * 4096, 0.0625f);
        // 6) softmax
        softmax_rows<<<dim3(4096), 256, 0, stream>>>(Sb, mask);
        // 7) Z partials: K-split x4 over L (grid 1280 -> 5 blocks/CU)
        zsplit<<<dim3(160, 8), 256, 0, stream>>>(Sb, Hbt, Zp);
        // 8) out = sum of 4 partials
        reduce4<<<dim3(5120), 256, 0, stream>>>(Zp, out, nZ / 4);
    } else if (ws_size >= need1) {
        gemm_proj<<<dim3(512, 1), 256, 0, stream>>>(H, Wk, Kb, 32768, 256, 1280);
        gemm_proj<<<dim3(64, 1), 256, 0, stream>>>(G, Wq, Qb, 4096, 256, 768);
        cvt_h<false><<<dim3(2048), 256, 0, stream>>>(H, Hbt, nullptr);
        gemm_bt16s<false><<<dim3(128, 8), 256, 0, stream>>>(
            Qb, Kb, Sb, 512, 4096, 256,
            (long)512 * 256, (long)4096 * 256, (long)512 * 4096, 0.0625f);
        softmax_rows<<<dim3(4096), 256, 0, stream>>>(Sb, mask);
        gemm_bt16s<true><<<dim3(40, 8), 256, 0, stream>>>(
            Sb, Hbt, out, 512, 1280, 4096,
            (long)512 * 4096, (long)1280 * 4096, (long)512 * 1280, 1.0f);
    } else {
        gemm_proj<<<dim3(512, 1), 256, 0, stream>>>(H, Wk, Kb, 32768, 256, 1280);
        gemm_proj<<<dim3(64, 1), 256, 0, stream>>>(G, Wq, Qb, 4096, 256, 768);
        gemm_bt16s<false><<<dim3(128, 8), 256, 0, stream>>>(
            Qb, Kb, Sb, 512, 4096, 256,
            (long)512 * 256, (long)4096 * 256, (long)512 * 4096, 0.0625f);
        softmax_rows<<<dim3(4096), 256, 0, stream>>>(Sb, mask);
        gemm_kn<<<dim3(80, 8), 256, 0, stream>>>(
            Sb, H, out, 512, 1280, 4096,
            (long)512 * 4096, (long)4096 * 1280, (long)512 * 1280);
    }
}

// Round 9
// 267.899 us; speedup vs baseline: 1.0286x; 1.0286x over previous
//
#include <hip/hip_runtime.h>
#include <hip/hip_bf16.h>
#include <stdint.h>

// B=8, L=4096, T=512, D_H=1280, D_G=768, D_P=256, scale = 1/16

typedef float f32x4 __attribute__((ext_vector_type(4)));
typedef short bf16x8 __attribute__((ext_vector_type(8)));

__device__ __forceinline__ unsigned short f2bf(float f) {
    __hip_bfloat16 h = __float2bfloat16(f);
    return __builtin_bit_cast(unsigned short, h);
}
__device__ __forceinline__ float bf2f(unsigned short h) {
    union { uint32_t u; float f; } v; v.u = ((uint32_t)h) << 16;
    return v.f;
}

// bijective XCD-chunk swizzle (gridDim.x % 8 == 0 at all call sites)
__device__ __forceinline__ int xcdswz(int bx, int nbx) {
    int cpx = nbx >> 3;
    return (bx & 7) * cpx + (bx >> 3);
}

// async global->LDS, 16B per lane; LDS dest = wave-uniform base + lane*16
__device__ __forceinline__ void gload16(const unsigned short* g, unsigned short* l) {
    __builtin_amdgcn_global_load_lds(
        (const __attribute__((address_space(1))) void*)g,
        (__attribute__((address_space(3))) void*)l,
        16, 0, 0);
}

// LDS index for f32-staged kernels (padded stride 40 + granule XOR swizzle)
__device__ __forceinline__ int lidx(int row, int kshort) {
    return row * 40 + (((kshort >> 3) ^ ((row >> 3) & 3)) << 3) + (kshort & 7);
}

// ---------------------------------------------------------------------------
// f32 -> bf16 contiguous convert (for Wk); n4 = count/4
// ---------------------------------------------------------------------------
__global__ __launch_bounds__(256)
void cvt_f32_bf16(const float* __restrict__ in, unsigned short* __restrict__ out, long n4)
{
    long i = (long)blockIdx.x * 256 + threadIdx.x;
    if (i >= n4) return;
    float4 v = ((const float4*)in)[i];
    ushort4 w;
    w.x = f2bf(v.x); w.y = f2bf(v.y); w.z = f2bf(v.z); w.w = f2bf(v.w);
    ((ushort4*)out)[i] = w;
}

// ---------------------------------------------------------------------------
// H [8][4096][1280] f32 -> Hbt [8][1280][4096] bf16 (transposed)
//                       -> Hb  [8][4096][1280] bf16 (row-major, coalesced)
// ---------------------------------------------------------------------------
template<bool WRITE_HB>
__global__ __launch_bounds__(256)
void cvt_h(const float* __restrict__ H, unsigned short* __restrict__ Hbt,
           unsigned short* __restrict__ Hb)
{
    __shared__ unsigned short lT[64 * 72];
    const int ntile = 64 * 20 * 8;
    for (int tileid = blockIdx.x; tileid < ntile; tileid += gridDim.x) {
        int tmp = tileid;
        const int dt = tmp % 20; tmp /= 20;
        const int lt = tmp % 64;
        const int b  = tmp / 64;
        const int l0 = lt * 64, d0 = dt * 64;
        const float* Hs = H + ((long)b * 4096 + l0) * 1280 + d0;
        #pragma unroll
        for (int it = 0; it < 4; ++it) {
            int chunk = it * 256 + threadIdx.x;
            int lr = chunk >> 4, dc4 = (chunk & 15) << 2;
            float4 v = *(const float4*)(Hs + (long)lr * 1280 + dc4);
            unsigned short w[4] = { f2bf(v.x), f2bf(v.y), f2bf(v.z), f2bf(v.w) };
            if constexpr (WRITE_HB) {
                ushort4 wb = { w[0], w[1], w[2], w[3] };
                *(ushort4*)(Hb + ((long)b * 4096 + l0 + lr) * 1280 + d0 + dc4) = wb;
            }
            #pragma unroll
            for (int j = 0; j < 4; ++j) {
                int d = dc4 + j;
                int sl = (lr & 15) | ((((lr >> 4) ^ (d >> 2)) & 3) << 4);
                lT[d * 72 + sl] = w[j];
            }
        }
        __syncthreads();
        {
            int drow = threadIdx.x >> 2, lc = threadIdx.x & 3;
            int slc = lc ^ ((drow >> 2) & 3);
            const uint4* src = (const uint4*)(lT + drow * 72 + slc * 16);
            unsigned short* dst = Hbt + ((long)b * 1280 + d0 + drow) * 4096 + l0 + lc * 16;
            uint4 v0 = src[0], v1 = src[1];
            *(uint4*)(dst)     = v0;
            *(uint4*)(dst + 8) = v1;
        }
        __syncthreads();
    }
}

// ---------------------------------------------------------------------------
// Projection GEMM: f32 inputs (cvt in staging), bf16 out. 128x128, BK=32.
// Used only for Q (small).
// ---------------------------------------------------------------------------
__global__ __launch_bounds__(256)
void gemm_proj(const float* __restrict__ Ap, const float* __restrict__ Bp,
               unsigned short* __restrict__ Cp, int M, int N, int K)
{
    __shared__ __align__(16) unsigned short lA[128 * 40];
    __shared__ __align__(16) unsigned short lB[128 * 40];

    const int bx = xcdswz(blockIdx.x, gridDim.x);
    const int nt = N >> 7;
    const int tm = bx / nt;
    const int tn = bx % nt;
    const int tid = threadIdx.x;
    const int lane = tid & 63, wv = tid >> 6;
    const int wr = wv >> 1, wc = wv & 1;
    const int fr = lane & 15, fk = lane >> 4;

    f32x4 acc[4][4] = {};

    for (int k0 = 0; k0 < K; k0 += 32) {
        {
            const float* A = Ap + (long)tm * 128 * K + k0;
            #pragma unroll
            for (int it = 0; it < 4; ++it) {
                int chunk = it * 256 + tid;
                int row = chunk >> 3;
                int kc  = (chunk & 7) << 2;
                const float4 v = *(const float4*)(A + (long)row * K + kc);
                ushort4 w;
                w.x = f2bf(v.x); w.y = f2bf(v.y); w.z = f2bf(v.z); w.w = f2bf(v.w);
                *(ushort4*)(&lA[lidx(row, kc)]) = w;
            }
        }
        {
            const float* B = Bp + (long)tn * 128 * K + k0;
            #pragma unroll
            for (int it = 0; it < 4; ++it) {
                int chunk = it * 256 + tid;
                int row = chunk >> 3;
                int kc  = (chunk & 7) << 2;
                const float4 v = *(const float4*)(B + (long)row * K + kc);
                ushort4 w;
                w.x = f2bf(v.x); w.y = f2bf(v.y); w.z = f2bf(v.z); w.w = f2bf(v.w);
                *(ushort4*)(&lB[lidx(row, kc)]) = w;
            }
        }
        __syncthreads();
        bf16x8 af[4], bfr[4];
        #pragma unroll
        for (int i = 0; i < 4; ++i)
            af[i] = *(const bf16x8*)(&lA[lidx(wr * 64 + i * 16 + fr, fk * 8)]);
        #pragma unroll
        for (int i = 0; i < 4; ++i)
            bfr[i] = *(const bf16x8*)(&lB[lidx(wc * 64 + i * 16 + fr, fk * 8)]);
        #pragma unroll
        for (int mi = 0; mi < 4; ++mi)
            #pragma unroll
            for (int ni = 0; ni < 4; ++ni)
                acc[mi][ni] = __builtin_amdgcn_mfma_f32_16x16x32_bf16(af[mi], bfr[ni], acc[mi][ni], 0, 0, 0);
        __syncthreads();
    }

    unsigned short* C = Cp + ((long)tm * 128) * N + (long)tn * 128;
    #pragma unroll
    for (int mi = 0; mi < 4; ++mi)
        #pragma unroll
        for (int ni = 0; ni < 4; ++ni)
            #pragma unroll
            for (int j = 0; j < 4; ++j) {
                int m = wr * 64 + mi * 16 + fk * 4 + j;
                int n = wc * 64 + ni * 16 + fr;
                C[(long)m * N + n] = f2bf(acc[mi][ni][j]);
            }
}

// ---------------------------------------------------------------------------
// All-bf16 C = scale*A@B^T, 2-PHASE DOUBLE-BUFFERED (T3 minimum recipe).
// Tile 128x128, BK=64, 4 waves 2x2. Per iter: STAGE(next buf) -> ds_read(cur)
// -> MFMA -> barrier (implicit vmcnt(0)+lgkmcnt(0) drain lands AFTER compute,
// hiding the staging latency). One barrier per K-step. LDS 64KB -> 2 blk/CU.
// ---------------------------------------------------------------------------
template<bool OF32>
__global__ __launch_bounds__(256)
void gemm_bt16d(const unsigned short* __restrict__ Ap, const unsigned short* __restrict__ Bp,
                void* __restrict__ Cp, int M, int N, int K,
                long sA, long sB, long sC, float scale)
{
    __shared__ __align__(16) unsigned short lA[2][128 * 64];   // 32KB
    __shared__ __align__(16) unsigned short lB[2][128 * 64];   // 32KB

    const int bx = xcdswz(blockIdx.x, gridDim.x);
    const int nt_ = N >> 7;
    const int tm = bx / nt_, tn = bx % nt_;
    const int b  = blockIdx.y;
    const int tid = threadIdx.x;
    const int lane = tid & 63, wv = tid >> 6;
    const int wr = wv >> 1, wc = wv & 1;
    const int fr = lane & 15, fk = lane >> 4;

    f32x4 acc[4][4] = {};

    const unsigned short* A0 = Ap + (long)b * sA + (long)tm * 128 * K;
    const unsigned short* B0 = Bp + (long)b * sB + (long)tn * 128 * K;

    // staging: 128 rows x 8 chunks(16B) per tile; pre-swizzled source chunk
    #define STAGE_D(bufi, kk0)                                                   \
        _Pragma("unroll")                                                        \
        for (int q = 0; q < 4; ++q) {                                            \
            int slot = wv * 256 + q * 64 + lane;                                 \
            int row = slot >> 3, c = slot & 7;                                   \
            int kc = (c ^ (row & 7)) << 3;                                       \
            gload16(A0 + (long)row * K + (kk0) + kc,                             \
                    &lA[bufi][(size_t)(wv * 256 + q * 64) * 8]);                 \
            gload16(B0 + (long)row * K + (kk0) + kc,                             \
                    &lB[bufi][(size_t)(wv * 256 + q * 64) * 8]);                 \
        }

    const int nt = K >> 6;
    STAGE_D(0, 0)
    __syncthreads();                       // drains vmcnt(0): buf0 ready

    for (int t = 0; t < nt; ++t) {
        const int cur = t & 1;
        if (t + 1 < nt) { STAGE_D(cur ^ 1, (t + 1) << 6) }   // in flight during compute
        const unsigned short* la = lA[cur];
        const unsigned short* lb = lB[cur];
        bf16x8 af[2][4], bfv[2][4];
        #pragma unroll
        for (int ks = 0; ks < 2; ++ks) {
            int csw = ((ks * 4 + fk) ^ (fr & 7)) << 3;
            #pragma unroll
            for (int i = 0; i < 4; ++i) {
                af[ks][i]  = *(const bf16x8*)(la + (wr * 64 + i * 16 + fr) * 64 + csw);
                bfv[ks][i] = *(const bf16x8*)(lb + (wc * 64 + i * 16 + fr) * 64 + csw);
            }
        }
        #pragma unroll
        for (int mi = 0; mi < 4; ++mi)
            #pragma unroll
            for (int ni = 0; ni < 4; ++ni)
                #pragma unroll
                for (int ks = 0; ks < 2; ++ks)
                    acc[mi][ni] = __builtin_amdgcn_mfma_f32_16x16x32_bf16(af[ks][mi], bfv[ks][ni], acc[mi][ni], 0, 0, 0);
        __syncthreads();                   // drain: next buf ready; reads of cur done
    }
    #undef STAGE_D

    if constexpr (OF32) {
        float* C = (float*)Cp + (long)b * sC + ((long)tm * 128) * N + (long)tn * 128;
        #pragma unroll
        for (int mi = 0; mi < 4; ++mi)
            #pragma unroll
            for (int ni = 0; ni < 4; ++ni)
                #pragma unroll
                for (int j = 0; j < 4; ++j) {
                    int m = wr * 64 + mi * 16 + fk * 4 + j;
                    int n = wc * 64 + ni * 16 + fr;
                    C[(long)m * N + n] = acc[mi][ni][j] * scale;
                }
    } else {
        unsigned short* C = (unsigned short*)Cp + (long)b * sC + ((long)tm * 128) * N + (long)tn * 128;
        #pragma unroll
        for (int mi = 0; mi < 4; ++mi)
            #pragma unroll
            for (int ni = 0; ni < 4; ++ni)
                #pragma unroll
                for (int j = 0; j < 4; ++j) {
                    int m = wr * 64 + mi * 16 + fk * 4 + j;
                    int n = wc * 64 + ni * 16 + fr;
                    C[(long)m * N + n] = f2bf(acc[mi][ni][j] * scale);
                }
    }
}

// ---------------------------------------------------------------------------
// Z partial GEMM, K-split x4, 2-PHASE DOUBLE-BUFFERED (same loop as bt16d).
// Grid (160,8): bx -> ks*40 + tn*4 + tm (tm fastest).
// ---------------------------------------------------------------------------
__global__ __launch_bounds__(256)
void zsplitd(const unsigned short* __restrict__ Sb, const unsigned short* __restrict__ Hbt,
             float* __restrict__ Zp)
{
    __shared__ __align__(16) unsigned short lA[2][128 * 64];
    __shared__ __align__(16) unsigned short lB[2][128 * 64];

    const int K = 4096, N = 1280, KS = 1024;
    const long nZ = (long)8 * 512 * 1280;

    const int bx = xcdswz(blockIdx.x, gridDim.x);
    const int tm = bx & 3;
    const int tn = (bx >> 2) % 10;
    const int ks = bx / 40;
    const int b  = blockIdx.y;
    const int tid = threadIdx.x;
    const int lane = tid & 63, wv = tid >> 6;
    const int wr = wv >> 1, wc = wv & 1;
    const int fr = lane & 15, fk = lane >> 4;

    f32x4 acc[4][4] = {};

    const unsigned short* A0 = Sb  + ((long)b * 512  + tm * 128) * K + ks * KS;
    const unsigned short* B0 = Hbt + ((long)b * 1280 + tn * 128) * K + ks * KS;

    #define STAGE_Z(bufi, kk0)                                                   \
        _Pragma("unroll")                                                        \
        for (int q = 0; q < 4; ++q) {                                            \
            int slot = wv * 256 + q * 64 + lane;                                 \
            int row = slot >> 3, c = slot & 7;                                   \
            int kc = (c ^ (row & 7)) << 3;                                       \
            gload16(A0 + (long)row * K + (kk0) + kc,                             \
                    &lA[bufi][(size_t)(wv * 256 + q * 64) * 8]);                 \
            gload16(B0 + (long)row * K + (kk0) + kc,                             \
                    &lB[bufi][(size_t)(wv * 256 + q * 64) * 8]);                 \
        }

    const int nt = KS >> 6;   // 16
    STAGE_Z(0, 0)
    __syncthreads();

    for (int t = 0; t < nt; ++t) {
        const int cur = t & 1;
        if (t + 1 < nt) { STAGE_Z(cur ^ 1, (t + 1) << 6) }
        const unsigned short* la = lA[cur];
        const unsigned short* lb = lB[cur];
        bf16x8 af[2][4], bfv[2][4];
        #pragma unroll
        for (int kk = 0; kk < 2; ++kk) {
            int csw = ((kk * 4 + fk) ^ (fr & 7)) << 3;
            #pragma unroll
            for (int i = 0; i < 4; ++i) {
                af[kk][i]  = *(const bf16x8*)(la + (wr * 64 + i * 16 + fr) * 64 + csw);
                bfv[kk][i] = *(const bf16x8*)(lb + (wc * 64 + i * 16 + fr) * 64 + csw);
            }
        }
        #pragma unroll
        for (int mi = 0; mi < 4; ++mi)
            #pragma unroll
            for (int ni = 0; ni < 4; ++ni)
                #pragma unroll
                for (int kk = 0; kk < 2; ++kk)
                    acc[mi][ni] = __builtin_amdgcn_mfma_f32_16x16x32_bf16(af[kk][mi], bfv[kk][ni], acc[mi][ni], 0, 0, 0);
        __syncthreads();
    }
    #undef STAGE_Z

    float* C = Zp + (long)ks * nZ + ((long)b * 512 + tm * 128) * N + tn * 128;
    #pragma unroll
    for (int mi = 0; mi < 4; ++mi)
        #pragma unroll
        for (int ni = 0; ni < 4; ++ni)
            #pragma unroll
            for (int j = 0; j < 4; ++j) {
                int m = wr * 64 + mi * 16 + fk * 4 + j;
                int n = wc * 64 + ni * 16 + fr;
                C[(long)m * N + n] = acc[mi][ni][j];
            }
}

// ---------------------------------------------------------------------------
// out = p0 + p1 + p2 + p3 (deterministic pairwise order), f32x4 elementwise
// ---------------------------------------------------------------------------
__global__ __launch_bounds__(256)
void reduce4(const float* __restrict__ p, float* __restrict__ out, long n4)
{
    long i = (long)blockIdx.x * 256 + threadIdx.x;
    if (i >= n4) return;
    const long s = n4;
    f32x4 a = ((const f32x4*)p)[i];
    f32x4 b = ((const f32x4*)p)[i + s];
    f32x4 c = ((const f32x4*)p)[i + 2 * s];
    f32x4 d = ((const f32x4*)p)[i + 3 * s];
    ((f32x4*)out)[i] = (a + b) + (c + d);
}

// ---------------------------------------------------------------------------
// Fallback Z-GEMM (small-ws path): C = A(bf16) @ B(f32,[K][N])
// ---------------------------------------------------------------------------
__global__ __launch_bounds__(256)
void gemm_kn(const unsigned short* __restrict__ Ap, const float* __restrict__ Bp,
             float* __restrict__ Cp, int M, int N, int K,
             long sA, long sB, long sC)
{
    __shared__ __align__(16) unsigned short lA[128 * 40];
    __shared__ __align__(16) unsigned short lB[64 * 40];

    const int bx = xcdswz(blockIdx.x, gridDim.x);
    const int mt = M >> 7;
    const int tm = bx % mt;
    const int tn = bx / mt;
    const int b  = blockIdx.y;
    const int tid = threadIdx.x;
    const int lane = tid & 63, wv = tid >> 6;
    const int wr = wv >> 1, wc = wv & 1;
    const int fr = lane & 15, fk = lane >> 4;

    f32x4 acc[4][2] = {};

    const unsigned short* A0 = Ap + (long)b * sA + (long)tm * 128 * K;
    const int nn    = tid & 63;
    const int khalf = tid >> 6;

    for (int k0 = 0; k0 < K; k0 += 32) {
        #pragma unroll
        for (int it = 0; it < 2; ++it) {
            int chunk = it * 256 + tid;
            int row = chunk >> 2;
            int kc  = (chunk & 3) << 3;
            *(uint4*)(&lA[lidx(row, kc)]) = *(const uint4*)(A0 + (long)row * K + k0 + kc);
        }
        {
            const float* Bb = Bp + (long)b * sB + (long)(k0 + khalf * 8) * N + (long)tn * 64 + nn;
            unsigned short t8[8];
            #pragma unroll
            for (int kk = 0; kk < 8; ++kk)
                t8[kk] = f2bf(Bb[(long)kk * N]);
            *(uint4*)(&lB[lidx(nn, khalf * 8)]) = *(uint4*)(&t8[0]);
        }
        __syncthreads();
        bf16x8 af[4], bfr[2];
        #pragma unroll
        for (int i = 0; i < 4; ++i)
            af[i] = *(const bf16x8*)(&lA[lidx(wr * 64 + i * 16 + fr, fk * 8)]);
        #pragma unroll
        for (int i = 0; i < 2; ++i)
            bfr[i] = *(const bf16x8*)(&lB[lidx(wc * 32 + i * 16 + fr, fk * 8)]);
        #pragma unroll
        for (int mi = 0; mi < 4; ++mi)
            #pragma unroll
            for (int ni = 0; ni < 2; ++ni)
                acc[mi][ni] = __builtin_amdgcn_mfma_f32_16x16x32_bf16(af[mi], bfr[ni], acc[mi][ni], 0, 0, 0);
        __syncthreads();
    }

    float* C = Cp + (long)b * sC + ((long)tm * 128) * N + (long)tn * 64;
    #pragma unroll
    for (int mi = 0; mi < 4; ++mi)
        #pragma unroll
        for (int ni = 0; ni < 2; ++ni)
            #pragma unroll
            for (int j = 0; j < 4; ++j) {
                int m = wr * 64 + mi * 16 + fk * 4 + j;
                int n = wc * 32 + ni * 16 + fr;
                C[(long)m * N + n] = acc[mi][ni][j];
            }
}

// ---------------------------------------------------------------------------
// Row softmax in place on S (bf16), rows of length 4096.
// ---------------------------------------------------------------------------
__global__ __launch_bounds__(256)
void softmax_rows(unsigned short* __restrict__ S, const unsigned char* __restrict__ mask)
{
    const int row = blockIdx.x;
    const int b = row >> 9;
    const long base = (long)row * 4096;
    const int tid = threadIdx.x, lane = tid & 63, wv = tid >> 6;
    __shared__ float red[8];

    uint4 s0 = *(const uint4*)(S + base + tid * 16);
    uint4 s1 = *(const uint4*)(S + base + tid * 16 + 8);
    uint4 mv = *(const uint4*)(mask + (long)b * 4096 + tid * 16);
    const unsigned char* mb = (const unsigned char*)&mv;

    unsigned int words[8] = { s0.x, s0.y, s0.z, s0.w, s1.x, s1.y, s1.z, s1.w };
    float x[16];
    #pragma unroll
    for (int i = 0; i < 8; ++i) {
        x[2 * i]     = bf2f((unsigned short)(words[i] & 0xffffu));
        x[2 * i + 1] = bf2f((unsigned short)(words[i] >> 16));
    }
    #pragma unroll
    for (int i = 0; i < 16; ++i)
        if (mb[i]) x[i] = -1e30f;

    float m = x[0];
    #pragma unroll
    for (int i = 1; i < 16; ++i) m = fmaxf(m, x[i]);
    #pragma unroll
    for (int off = 32; off; off >>= 1) m = fmaxf(m, __shfl_xor(m, off));
    if (lane == 0) red[wv] = m;
    __syncthreads();
    m = fmaxf(fmaxf(red[0], red[1]), fmaxf(red[2], red[3]));

    float p[16];
    float s = 0.f;
    #pragma unroll
    for (int i = 0; i < 16; ++i) { p[i] = __expf(x[i] - m); s += p[i]; }
    #pragma unroll
    for (int off = 32; off; off >>= 1) s += __shfl_xor(s, off);
    if (lane == 0) red[4 + wv] = s;
    __syncthreads();
    s = (red[4] + red[5]) + (red[6] + red[7]);
    const float inv = 1.0f / s;

    unsigned int ow[8];
    #pragma unroll
    for (int i = 0; i < 8; ++i) {
        unsigned int lo = f2bf(p[2 * i] * inv);
        unsigned int hi = f2bf(p[2 * i + 1] * inv);
        ow[i] = lo | (hi << 16);
    }
    uint4 o0 = { ow[0], ow[1], ow[2], ow[3] };
    uint4 o1 = { ow[4], ow[5], ow[6], ow[7] };
    *(uint4*)(S + base + tid * 16)     = o0;
    *(uint4*)(S + base + tid * 16 + 8) = o1;
}

// ---------------------------------------------------------------------------
extern "C" void kernel_launch(void* const* d_in, const int* in_sizes, int n_in,
                              void* d_out, int out_size, void* d_ws, size_t ws_size,
                              hipStream_t stream)
{
    const float*         H    = (const float*)d_in[0];
    const float*         G    = (const float*)d_in[1];
    const unsigned char* mask = (const unsigned char*)d_in[2];
    const float*         Wk   = (const float*)d_in[3];
    const float*         Wq   = (const float*)d_in[4];
    float*               out  = (float*)d_out;

    const long nK = (long)8 * 4096 * 256;     // Kb
    const long nQ = (long)8 * 512 * 256;      // Qb
    const long nS = (long)8 * 512 * 4096;     // Sb
    const long nH = (long)8 * 1280 * 4096;    // Hbt / Hb each
    const long nW = (long)256 * 1280;         // Wkb
    const long nZ = (long)8 * 512 * 1280;     // Z elems (f32)

    unsigned short* Kb  = (unsigned short*)d_ws;
    unsigned short* Qb  = Kb + nK;
    unsigned short* Sb  = Qb + nQ;
    unsigned short* Hbt = Sb + nS;
    unsigned short* Hb  = Hbt + nH;
    unsigned short* Wkb = Hb + nH;
    float*          Zp  = (float*)Hb;         // reuse: Hb dead after K-proj;
                                              // 4 * nZ * 4B == nH * 2B exactly

    const size_t need2 = (size_t)(nK + nQ + nS + nH + nH + nW) * 2;  // ~221 MB
    const size_t need1 = (size_t)(nK + nQ + nS + nH) * 2;            // ~137 MB

    if (ws_size >= need2) {
        // 1) Wkb = bf16(Wk)
        cvt_f32_bf16<<<dim3(320), 256, 0, stream>>>(Wk, Wkb, nW / 4);
        // 2) Hb (row-major bf16) + Hbt (transposed bf16) from H, single pass
        cvt_h<true><<<dim3(2048), 256, 0, stream>>>(H, Hbt, Hb);
        // 3) K = Hb @ Wkb^T  (M=32768,N=256,K=1280), 2-phase dbuf
        gemm_bt16d<false><<<dim3(512, 1), 256, 0, stream>>>(
            Hb, Wkb, Kb, 32768, 256, 1280, 0, 0, 0, 1.0f);
        // 4) Q = G @ Wq^T (M=4096,N=256,K=768), f32-staged (small)
        gemm_proj<<<dim3(64, 1), 256, 0, stream>>>(G, Wq, Qb, 4096, 256, 768);
        // 5) S = Q @ K^T * scale  per batch (M=512,N=4096,K=256), 2-phase dbuf
        gemm_bt16d<false><<<dim3(128, 8), 256, 0, stream>>>(
            Qb, Kb, Sb, 512, 4096, 256,
            (long)512 * 256, (long)4096 * 256, (long)512 * 4096, 0.0625f);
        // 6) softmax
        softmax_rows<<<dim3(4096), 256, 0, stream>>>(Sb, mask);
        // 7) Z partials: K-split x4, 2-phase dbuf
        zsplitd<<<dim3(160, 8), 256, 0, stream>>>(Sb, Hbt, Zp);
        // 8) out = sum of 4 partials
        reduce4<<<dim3(5120), 256, 0, stream>>>(Zp, out, nZ / 4);
    } else if (ws_size >= need1) {
        gemm_proj<<<dim3(512, 1), 256, 0, stream>>>(H, Wk, Kb, 32768, 256, 1280);
        gemm_proj<<<dim3(64, 1), 256, 0, stream>>>(G, Wq, Qb, 4096, 256, 768);
        cvt_h<false><<<dim3(2048), 256, 0, stream>>>(H, Hbt, nullptr);
        gemm_bt16d<false><<<dim3(128, 8), 256, 0, stream>>>(
            Qb, Kb, Sb, 512, 4096, 256,
            (long)512 * 256, (long)4096 * 256, (long)512 * 4096, 0.0625f);
        softmax_rows<<<dim3(4096), 256, 0, stream>>>(Sb, mask);
        gemm_bt16d<true><<<dim3(40, 8), 256, 0, stream>>>(
            Sb, Hbt, out, 512, 1280, 4096,
            (long)512 * 4096, (long)1280 * 4096, (long)512 * 1280, 1.0f);
    } else {
        gemm_proj<<<dim3(512, 1), 256, 0, stream>>>(H, Wk, Kb, 32768, 256, 1280);
        gemm_proj<<<dim3(64, 1), 256, 0, stream>>>(G, Wq, Qb, 4096, 256, 768);
        gemm_bt16d<false><<<dim3(128, 8), 256, 0, stream>>>(
            Qb, Kb, Sb, 512, 4096, 256,
            (long)512 * 256, (long)4096 * 256, (long)512 * 4096, 0.0625f);
        softmax_rows<<<dim3(4096), 256, 0, stream>>>(Sb, mask);
        gemm_kn<<<dim3(80, 8), 256, 0, stream>>>(
            Sb, H, out, 512, 1280, 4096,
            (long)512 * 4096, (long)4096 * 1280, (long)512 * 1280);
    }
}